// Round 1
// baseline (121.013 us; speedup 1.0000x reference)
//
#include <hip/hip_runtime.h>

#define S_COEF 0.025f
#define EPS_C  1e-6f

// One wave (64 lanes) per (b,f) row. Each lane owns 4 consecutive time steps
// per 256-element group; EMA recurrence parallelized via rescaled prefix-sum
// (coefficient is uniform u = 1-S, so the affine-scan reduces to a prefix sum
// of b_j * u^{-4j}, dynamic range u^{-252} ~= 590 -- safe in fp32).
__global__ __launch_bounds__(256) void pcen_kernel(
    const float* __restrict__ x,
    const float* __restrict__ p_la,
    const float* __restrict__ p_ld,
    const float* __restrict__ p_lr,
    float* __restrict__ out,
    int rows, int T)
{
    const int lane = threadIdx.x & 63;
    const int wid  = blockIdx.x * (blockDim.x >> 6) + (threadIdx.x >> 6);
    if (wid >= rows) return;

    const float alpha = fminf(fmaxf(__expf(p_la[0]), 0.01f), 1.0f);
    const float delta = fminf(fmaxf(__expf(p_ld[0]), 0.01f), 5.0f);
    const float r     = fminf(fmaxf(__expf(p_lr[0]), 0.01f), 1.0f);
    const float dr    = __expf(r * __logf(delta));   // delta^r

    const float u     = 1.0f - S_COEF;               // 0.975
    const float u4    = u * u * u * u;
    const float uinv4 = 1.0f / u4;
    // per-lane constants: u^{-4*lane} and u^{4*lane}
    const float winv = __expf(-4.0f * (float)lane * __logf(u));
    const float ul4  = 1.0f / winv;

    const float* __restrict__ xr = x   + (size_t)wid * T;
    float* __restrict__       orr = out + (size_t)wid * T;

    const int ngroups = (T + 255) >> 8;              // 32 for T=8000
    float carry = 0.0f;

    int idx = lane * 4;
    float4 cur = (idx < T) ? *(const float4*)(xr + idx)
                           : make_float4(0.f, 0.f, 0.f, 0.f);

    for (int g = 0; g < ngroups; ++g) {
        const int base = g << 8;                     // g*256
        // prefetch next group (address-independent of the carry chain)
        const int nidx = base + 256 + lane * 4;
        float4 nxt = (nidx < T) ? *(const float4*)(xr + nidx)
                                : make_float4(0.f, 0.f, 0.f, 0.f);

        const float e0 = __expf(cur.x);
        const float e1 = __expf(cur.y);
        const float e2 = __expf(cur.z);
        const float e3 = __expf(cur.w);

        // local 4-step EMA scan with zero initial state -> b
        float b = S_COEF * e0;
        b = u * b + S_COEF * e1;
        b = u * b + S_COEF * e2;
        b = u * b + S_COEF * e3;

        // inclusive prefix sum across lanes of b * u^{-4*lane}
        const float scaled = b * winv;
        float ps = scaled;
        #pragma unroll
        for (int d = 1; d < 64; d <<= 1) {
            float n = __shfl_up(ps, d, 64);
            if (lane >= d) ps += n;
        }

        // incoming EMA state for this lane:
        //   m_in = u^{4*lane} * (carry + psum_exclusive * u^{-4})
        const float m_in = ul4 * (carry + (ps - scaled) * uinv4);

        // replay the 4 steps with the true incoming state
        const float m0 = u * m_in + S_COEF * e0;
        const float m1 = u * m0   + S_COEF * e1;
        const float m2 = u * m1   + S_COEF * e2;
        const float m3 = u * m2   + S_COEF * e3;

        carry = __shfl(m3, 63, 64);                  // state leaving this group

        // out = (e * (EPS+M)^(-alpha) + delta)^r - delta^r
        const float d0 = __expf(-alpha * __logf(EPS_C + m0));
        const float d1 = __expf(-alpha * __logf(EPS_C + m1));
        const float d2 = __expf(-alpha * __logf(EPS_C + m2));
        const float d3 = __expf(-alpha * __logf(EPS_C + m3));

        const float o0 = __expf(r * __logf(e0 * d0 + delta)) - dr;
        const float o1 = __expf(r * __logf(e1 * d1 + delta)) - dr;
        const float o2 = __expf(r * __logf(e2 * d2 + delta)) - dr;
        const float o3 = __expf(r * __logf(e3 * d3 + delta)) - dr;

        if (base + lane * 4 < T)
            *(float4*)(orr + base + lane * 4) = make_float4(o0, o1, o2, o3);

        cur = nxt;
    }
}

extern "C" void kernel_launch(void* const* d_in, const int* in_sizes, int n_in,
                              void* d_out, int out_size, void* d_ws, size_t ws_size,
                              hipStream_t stream) {
    const float* x  = (const float*)d_in[0];
    const float* la = (const float*)d_in[1];
    const float* ld = (const float*)d_in[2];
    const float* lr = (const float*)d_in[3];
    float* out = (float*)d_out;

    const int T    = 8000;
    const int rows = in_sizes[0] / T;        // 64*128 = 8192
    const int wavesPerBlock = 4;             // blockDim 256
    const int blocks = (rows + wavesPerBlock - 1) / wavesPerBlock;

    hipLaunchKernelGGL(pcen_kernel, dim3(blocks), dim3(256), 0, stream,
                       x, la, ld, lr, out, rows, T);
}

// Round 3
// 85.938 us; speedup vs baseline: 1.4082x; 1.4082x over previous
//
#include <hip/hip_runtime.h>

#define S_COEF 0.025f
#define EPS_C  1e-6f
#define L2E    1.4426950408889634f   // log2(e)

typedef float f32x4 __attribute__((ext_vector_type(4)));

__device__ __forceinline__ float fexp2(float v) { return __builtin_amdgcn_exp2f(v); }
__device__ __forceinline__ float flog2(float v) { return __builtin_amdgcn_logf(v); }

// One wave per (b,f) row; 4 consecutive t per lane per 256-wide group.
// EMA recurrence parallelized via rescaled shuffle prefix-sum (u uniform).
// All pointwise pow-math in native base-2 (v_exp_f32/v_log_f32), fused as
//   e*(EPS+M)^-alpha = exp2(x*log2e - alpha*log2(M+EPS)).
__global__ __launch_bounds__(256) void pcen_kernel(
    const float* __restrict__ x,
    const float* __restrict__ p_la,
    const float* __restrict__ p_ld,
    const float* __restrict__ p_lr,
    float* __restrict__ out,
    int rows, int T)
{
    const int lane = threadIdx.x & 63;
    const int wid  = blockIdx.x * (blockDim.x >> 6) + (threadIdx.x >> 6);
    if (wid >= rows) return;

    const float alpha = fminf(fmaxf(__expf(p_la[0]), 0.01f), 1.0f);
    const float delta = fminf(fmaxf(__expf(p_ld[0]), 0.01f), 5.0f);
    const float r     = fminf(fmaxf(__expf(p_lr[0]), 0.01f), 1.0f);
    const float dr    = fexp2(r * flog2(delta));     // delta^r

    const float u     = 1.0f - S_COEF;               // 0.975
    const float u4    = u * u * u * u;
    const float uinv4 = 1.0f / u4;
    const float log2u = flog2(u);
    const float winv  = fexp2(-4.0f * (float)lane * log2u);  // u^(-4*lane)
    const float ul4   = fexp2( 4.0f * (float)lane * log2u);  // u^(+4*lane)

    const float* __restrict__ xr  = x   + (size_t)wid * T;
    float* __restrict__       orr = out + (size_t)wid * T;

    const int ngroups = (T + 255) >> 8;              // 32 for T=8000
    const int myoff   = lane * 4;
    float carry = 0.0f;

    f32x4 cur = (myoff < T) ? *(const f32x4*)(xr + myoff)
                            : (f32x4){0.f, 0.f, 0.f, 0.f};

    for (int g = 0; g < ngroups; ++g) {
        const int base = g << 8;
        const int nidx = base + 256 + myoff;
        f32x4 nxt = (nidx < T) ? *(const f32x4*)(xr + nidx)
                               : (f32x4){0.f, 0.f, 0.f, 0.f};

        // energies in base-2 domain; keep xl for the fused output pow
        const float xl0 = cur.x * L2E, xl1 = cur.y * L2E;
        const float xl2 = cur.z * L2E, xl3 = cur.w * L2E;
        const float e0 = fexp2(xl0), e1 = fexp2(xl1);
        const float e2 = fexp2(xl2), e3 = fexp2(xl3);

        const float se0 = S_COEF * e0, se1 = S_COEF * e1;
        const float se2 = S_COEF * e2, se3 = S_COEF * e3;

        // local 4-step EMA with zero initial state
        float b = se0;
        b = fmaf(u, b, se1);
        b = fmaf(u, b, se2);
        b = fmaf(u, b, se3);

        // inclusive prefix sum of b * u^(-4*lane)
        const float scaled = b * winv;
        float ps = scaled;
        #pragma unroll
        for (int d = 1; d < 64; d <<= 1) {
            float n = __shfl_up(ps, d, 64);
            if (lane >= d) ps += n;
        }

        // incoming state: m_in = u^(4*lane) * (carry + excl_prefix * u^(-4))
        const float m_in = ul4 * fmaf(ps - scaled, uinv4, carry);

        const float m0 = fmaf(u, m_in, se0);
        const float m1 = fmaf(u, m0,   se1);
        const float m2 = fmaf(u, m1,   se2);
        const float m3 = fmaf(u, m2,   se3);

        carry = __shfl(m3, 63, 64);

        // ed = e*(EPS+m)^(-alpha) = exp2(xl - alpha*log2(m+EPS))
        const float ed0 = fexp2(fmaf(-alpha, flog2(m0 + EPS_C), xl0));
        const float ed1 = fexp2(fmaf(-alpha, flog2(m1 + EPS_C), xl1));
        const float ed2 = fexp2(fmaf(-alpha, flog2(m2 + EPS_C), xl2));
        const float ed3 = fexp2(fmaf(-alpha, flog2(m3 + EPS_C), xl3));

        // o = (ed + delta)^r - delta^r
        const float o0 = fexp2(r * flog2(ed0 + delta)) - dr;
        const float o1 = fexp2(r * flog2(ed1 + delta)) - dr;
        const float o2 = fexp2(r * flog2(ed2 + delta)) - dr;
        const float o3 = fexp2(r * flog2(ed3 + delta)) - dr;

        if (base + myoff < T) {
            f32x4 o4 = {o0, o1, o2, o3};
            __builtin_nontemporal_store(o4, (f32x4*)(orr + base + myoff));
        }
        cur = nxt;
    }
}

extern "C" void kernel_launch(void* const* d_in, const int* in_sizes, int n_in,
                              void* d_out, int out_size, void* d_ws, size_t ws_size,
                              hipStream_t stream) {
    const float* x  = (const float*)d_in[0];
    const float* la = (const float*)d_in[1];
    const float* ld = (const float*)d_in[2];
    const float* lr = (const float*)d_in[3];
    float* out = (float*)d_out;

    const int T    = 8000;
    const int rows = in_sizes[0] / T;        // 64*128 = 8192
    const int wavesPerBlock = 4;             // blockDim 256
    const int blocks = (rows + wavesPerBlock - 1) / wavesPerBlock;

    hipLaunchKernelGGL(pcen_kernel, dim3(blocks), dim3(256), 0, stream,
                       x, la, ld, lr, out, rows, T);
}